// Round 2
// 857.196 us; speedup vs baseline: 1.3982x; 1.3982x over previous
//
#include <hip/hip_runtime.h>
#include <math.h>

typedef __attribute__((ext_vector_type(8))) __bf16 bf16_8;
typedef __attribute__((ext_vector_type(4))) float f32x4;

#define WS_HPROJ 0
#define WS_BT    16777216
#define WS_WRT   19398656
#define WS_CT    19791872

__device__ __forceinline__ float gelu_f(float x) {
    return 0.5f * x * (1.0f + erff(0.70710678118654752440f * x));
}

__device__ __forceinline__ void exp_se3_dev(const float xi[6], float R[9], float t[3]) {
    float wx = xi[0], wy = xi[1], wz = xi[2];
    float vx = xi[3], vy = xi[4], vz = xi[5];
    float ww = wx*wx + wy*wy + wz*wz;
    float th2 = ww + 1e-20f;
    float th = sqrtf(th2);
    float A, Bc, Cc;
    if (th < 1e-3f) {
        A = 1.f - th2*(1.f/6.f);
        Bc = 0.5f - th2*(1.f/24.f);
        Cc = (1.f/6.f) - th2*(1.f/120.f);
    } else {
        float s = sinf(th), c = cosf(th);
        A = s/th;
        Bc = (1.f - c)/th2;
        Cc = (th - s)/(th2*th);
    }
    float W2[9] = { wx*wx - ww, wx*wy,       wx*wz,
                    wy*wx,      wy*wy - ww,  wy*wz,
                    wz*wx,      wz*wy,       wz*wz - ww };
    R[0] = 1.f + Bc*W2[0];  R[1] = -A*wz + Bc*W2[1]; R[2] =  A*wy + Bc*W2[2];
    R[3] =  A*wz + Bc*W2[3]; R[4] = 1.f + Bc*W2[4];  R[5] = -A*wx + Bc*W2[5];
    R[6] = -A*wy + Bc*W2[6]; R[7] =  A*wx + Bc*W2[7]; R[8] = 1.f + Bc*W2[8];
    float V[9];
    V[0] = 1.f + Cc*W2[0];   V[1] = -Bc*wz + Cc*W2[1]; V[2] =  Bc*wy + Cc*W2[2];
    V[3] =  Bc*wz + Cc*W2[3]; V[4] = 1.f + Cc*W2[4];   V[5] = -Bc*wx + Cc*W2[5];
    V[6] = -Bc*wy + Cc*W2[6]; V[7] =  Bc*wx + Cc*W2[7]; V[8] = 1.f + Cc*W2[8];
    t[0] = V[0]*vx + V[1]*vy + V[2]*vz;
    t[1] = V[3]*vx + V[4]*vy + V[5]*vz;
    t[2] = V[6]*vx + V[7]*vy + V[8]*vz;
}

__device__ __forceinline__ void log_se3_dev(const float R[9], const float p[3], float xi[6]) {
    float tr = R[0] + R[4] + R[8];
    float c = 0.5f*(tr - 1.f);
    c = fminf(fmaxf(c, -1.f + 1e-7f), 1.f - 1e-7f);
    float th = acosf(c);
    float fac, D;
    if (th < 1e-3f) {
        fac = 0.5f + th*th*(1.f/12.f);
        D = 1.f/12.f;
    } else {
        float s = sinf(th), co = cosf(th);
        fac = th/(2.f*s);
        D = (1.f - th*s/(2.f*(1.f - co)))/(th*th);
    }
    float wx = fac*(R[7] - R[5]);
    float wy = fac*(R[2] - R[6]);
    float wz = fac*(R[3] - R[1]);
    float ww = wx*wx + wy*wy + wz*wz;
    float W2[9] = { wx*wx - ww, wx*wy,       wx*wz,
                    wy*wx,      wy*wy - ww,  wy*wz,
                    wz*wx,      wz*wy,       wz*wz - ww };
    float Vi[9];
    Vi[0] = 1.f + D*W2[0];    Vi[1] =  0.5f*wz + D*W2[1]; Vi[2] = -0.5f*wy + D*W2[2];
    Vi[3] = -0.5f*wz + D*W2[3]; Vi[4] = 1.f + D*W2[4];    Vi[5] =  0.5f*wx + D*W2[5];
    Vi[6] =  0.5f*wy + D*W2[6]; Vi[7] = -0.5f*wx + D*W2[7]; Vi[8] = 1.f + D*W2[8];
    xi[0] = wx; xi[1] = wy; xi[2] = wz;
    xi[3] = Vi[0]*p[0] + Vi[1]*p[1] + Vi[2]*p[2];
    xi[4] = Vi[3]*p[0] + Vi[4]*p[1] + Vi[5]*p[2];
    xi[5] = Vi[6]*p[0] + Vi[7]*p[1] + Vi[8]*p[2];
}

// ---------------------------------------------------------------------------
// prep_frag: pack weights into MFMA-fragment order (bf16).
//  BT2 tile t = s*20 + ntg  (s = k/32 in 0..127, ntg in 0..19 over 320 cols):
//    BT2[t*512 + l*8 + e] = Wfull[k = s*32 + (l>>4)*8 + e][col = ntg*16 + (l&15)]
//    where Wfull = W0[:4096] cols 0..255 | gW1 cols 256..319
//  WrT2 tile t2 = L*128 + sl*16 + ntg (sl in 0..7, ntg in 0..15):
//    WrT2[t2*512 + l*8 + e] = Wr[L][k = sl*32 + (l>>4)*8 + e][col = ntg*16 + (l&15)]
// ---------------------------------------------------------------------------
__global__ void prep_frag(const float* __restrict__ W0, const float* __restrict__ gW1,
                          const float* __restrict__ Wr, __bf16* __restrict__ BT2,
                          __bf16* __restrict__ WrT2) {
    const int tid = threadIdx.x;
    const int l = tid & 63, q = l >> 4, ln = l & 15;
    if (blockIdx.x < 640) {
        const int t = blockIdx.x * 4 + (tid >> 6);
        const int s = t / 20, ntg = t % 20;
        const int col = ntg*16 + ln;
        const int kbase = s*32 + q*8;
        bf16_8 o;
        if (col < 256) {
            #pragma unroll
            for (int e = 0; e < 8; ++e) o[e] = (__bf16)W0[(size_t)(kbase+e)*256 + col];
        } else {
            #pragma unroll
            for (int e = 0; e < 8; ++e) o[e] = (__bf16)gW1[(size_t)(kbase+e)*64 + (col-256)];
        }
        *(bf16_8*)(BT2 + (size_t)t*512 + l*8) = o;
    } else {
        const int t2 = (blockIdx.x - 640) * 4 + (tid >> 6);
        const int L = t2 >> 7, rem = t2 & 127, sl = rem >> 4, ntg = rem & 15;
        const int col = ntg*16 + ln;
        const int kbase = sl*32 + q*8;
        bf16_8 o;
        #pragma unroll
        for (int e = 0; e < 8; ++e)
            o[e] = (__bf16)Wr[(size_t)L*65536 + (size_t)(kbase+e)*256 + col];
        *(bf16_8*)(WrT2 + (size_t)t2*512 + l*8) = o;
    }
}

// ct[s][col] = b0[col] + temb(s/ns) @ W0[4102:4166]
__global__ void prep_ct(const float* __restrict__ W0, const float* __restrict__ b0,
                        const int* __restrict__ nsp, float* __restrict__ ct) {
    int s = blockIdx.x;
    int ns = *nsp;
    if (s >= ns) return;
    int col = threadIdx.x;
    float t = (float)s / (float)ns;
    float acc = b0[col];
    #pragma unroll
    for (int d = 0; d < 32; d++) {
        float f = expf((float)d * -0.29710775393471563f);  // -ln(10000)/31
        float e = t * f;
        acc += sinf(e) * W0[(size_t)(4102 + d)*256 + col];
        acc += cosf(e) * W0[(size_t)(4134 + d)*256 + col];
    }
    ct[s*256 + col] = acc;
}

// ---------------------------------------------------------------------------
// k2: h_proj = h @ W0[:4096] + fused gripper head.
// LDS-free / barrier-free MFMA: B-frags direct from L2 (fragment-packed BT2),
// A-frags direct from h (fp32->bf16 in regs). M-tile 32, grid 512 -> 2 blk/CU.
// Each wave computes all 32 rows x 5 col-tiles (ntg = w + jn*4).
// ---------------------------------------------------------------------------
__device__ __forceinline__ void k2_loada(float4 (&A)[2][2][2], const float* hbase, int st) {
    #pragma unroll
    for (int mt = 0; mt < 2; ++mt)
        #pragma unroll
        for (int kk = 0; kk < 2; ++kk) {
            const float* p = hbase + (size_t)mt*16*4096 + st*64 + kk*32;
            A[mt][kk][0] = *(const float4*)p;
            A[mt][kk][1] = *(const float4*)(p + 4);
        }
}
__device__ __forceinline__ void k2_loadb(bf16_8 (&Bv)[2][5], const __bf16* bbase, int st) {
    #pragma unroll
    for (int kk = 0; kk < 2; ++kk)
        #pragma unroll
        for (int jn = 0; jn < 5; ++jn)
            Bv[kk][jn] = *(const bf16_8*)(bbase + (size_t)((st*2 + kk)*20 + jn*4)*512);
}
__device__ __forceinline__ void k2_mm(f32x4 (&acc)[2][5], const float4 (&A)[2][2][2],
                                      const bf16_8 (&Bv)[2][5]) {
    #pragma unroll
    for (int kk = 0; kk < 2; ++kk) {
        bf16_8 af[2];
        #pragma unroll
        for (int mt = 0; mt < 2; ++mt) {
            af[mt][0] = (__bf16)A[mt][kk][0].x; af[mt][1] = (__bf16)A[mt][kk][0].y;
            af[mt][2] = (__bf16)A[mt][kk][0].z; af[mt][3] = (__bf16)A[mt][kk][0].w;
            af[mt][4] = (__bf16)A[mt][kk][1].x; af[mt][5] = (__bf16)A[mt][kk][1].y;
            af[mt][6] = (__bf16)A[mt][kk][1].z; af[mt][7] = (__bf16)A[mt][kk][1].w;
        }
        #pragma unroll
        for (int mt = 0; mt < 2; ++mt)
            #pragma unroll
            for (int jn = 0; jn < 5; ++jn)
                acc[mt][jn] = __builtin_amdgcn_mfma_f32_16x16x32_bf16(af[mt], Bv[kk][jn], acc[mt][jn], 0, 0, 0);
    }
}

__launch_bounds__(256, 2)
__global__ void k2(const float* __restrict__ h, const __bf16* __restrict__ BT2,
                   const float* __restrict__ gb1, const float* __restrict__ gW2,
                   const float* __restrict__ gb2, float* __restrict__ hproj,
                   float* __restrict__ grip) {
    __shared__ float gpart[32][4];

    const int tid = threadIdx.x;
    const int w = tid >> 6;
    const int l = tid & 63;
    const int q = l >> 4;
    const int ln = l & 15;
    const int m0 = blockIdx.x * 32;

    const float*  hbase = h + (size_t)(m0 + ln)*4096 + q*8;
    const __bf16* bbase = BT2 + (size_t)w*512 + (size_t)l*8;

    f32x4 acc[2][5];
    const f32x4 zv = {0.f, 0.f, 0.f, 0.f};
    #pragma unroll
    for (int a = 0; a < 2; ++a)
        #pragma unroll
        for (int b = 0; b < 5; ++b) acc[a][b] = zv;

    float4 A0[2][2][2], A1[2][2][2];
    bf16_8 B0[2][5], B1[2][5];
    k2_loada(A0, hbase, 0); k2_loadb(B0, bbase, 0);
    for (int st = 0; st < 64; st += 2) {
        if ((st & 7) == 0 && st) __syncthreads();   // keep waves loosely lockstep for L2 reuse
        k2_loada(A1, hbase, st + 1); k2_loadb(B1, bbase, st + 1);
        k2_mm(acc, A0, B0);
        if (st < 62) { k2_loada(A0, hbase, st + 2); k2_loadb(B0, bbase, st + 2); }
        k2_mm(acc, A1, B1);
    }

    // epilogue: h_proj columns (jn 0..3)
    #pragma unroll
    for (int mt = 0; mt < 2; ++mt)
        #pragma unroll
        for (int jn = 0; jn < 4; ++jn) {
            int col = (w + jn*4)*16 + ln;
            #pragma unroll
            for (int r = 0; r < 4; ++r) {
                int row = mt*16 + q*4 + r;
                hproj[(size_t)(m0 + row)*256 + col] = acc[mt][jn][r];
            }
        }
    // gripper columns (jn = 4 -> ntg = w+16 -> gW1 cols w*16..w*16+15)
    {
        int cg = w*16 + ln;
        float b1v = gb1[cg];
        float w2v = gW2[cg];
        float ps[2][4];
        #pragma unroll
        for (int mt = 0; mt < 2; ++mt)
            #pragma unroll
            for (int r = 0; r < 4; ++r)
                ps[mt][r] = gelu_f(acc[mt][4][r] + b1v) * w2v;
        #pragma unroll
        for (int off = 1; off < 16; off <<= 1)
            #pragma unroll
            for (int mt = 0; mt < 2; ++mt)
                #pragma unroll
                for (int r = 0; r < 4; ++r)
                    ps[mt][r] += __shfl_xor(ps[mt][r], off, 64);
        if (ln == 0)
            #pragma unroll
            for (int mt = 0; mt < 2; ++mt)
                #pragma unroll
                for (int r = 0; r < 4; ++r)
                    gpart[mt*16 + q*4 + r][w] = ps[mt][r];
    }
    __syncthreads();
    if (tid < 32) {
        float g = gpart[tid][0] + gpart[tid][1] + gpart[tid][2] + gpart[tid][3] + gb2[0];
        grip[m0 + tid] = 1.f / (1.f + expf(-g));
    }
}

// ---------------------------------------------------------------------------
// k3: persistent 10-step MLP + SE3 integrator. grid 512 x 256; 32 rows/WG,
// 2 blocks/CU. W-fragments loaded straight from L2 (WrT2) -> no per-slice
// LDS staging, no per-slice barriers.
// ---------------------------------------------------------------------------
__launch_bounds__(256, 2)
__global__ void k3(const float* __restrict__ hproj,
                   const __bf16* __restrict__ WrT2,
                   const float* __restrict__ ct,
                   const float* __restrict__ W0,
                   const float* __restrict__ Wout,
                   const float* __restrict__ bout,
                   const float* __restrict__ br,
                   const float* __restrict__ gr,
                   const float* __restrict__ ber,
                   const float* __restrict__ g0,
                   const float* __restrict__ be0,
                   const float* __restrict__ xi0,
                   const int* __restrict__ nsp,
                   float* __restrict__ out) {
    __shared__ __align__(16) __bf16 Ysh[32*264];   // 16896 B
    __shared__ float xiL[32*6];                    //   768 B
    __shared__ float rowred[32*16];                //  2048 B
    __shared__ float vpart[32*8*6];                //  6144 B
    __shared__ __align__(16) __bf16 woutT[6*256];  //  3072 B
    __shared__ float Xsh[32][12];                  //  1536 B
    __shared__ float ctL[256];                     //  1024 B
    __shared__ __align__(16) __bf16 w0xiL[6*256];  //  3072 B

    const int tid = threadIdx.x;
    const int w = tid >> 6;
    const int l = tid & 63;
    const int q = l >> 4;
    const int ln = l & 15;
    const int m0 = blockIdx.x * 32;
    const int ns = *nsp;
    const float dt = 1.0f / (float)ns;

    const int prow = tid >> 3;          // 0..31
    const int pcb  = (tid & 7) * 32;    // 32-col chunk

    if (tid < 32) {
        float xi[6];
        #pragma unroll
        for (int j = 0; j < 6; ++j) xi[j] = 0.1f * xi0[(size_t)(m0 + tid)*6 + j];
        float R[9], tt[3];
        exp_se3_dev(xi, R, tt);
        #pragma unroll
        for (int j = 0; j < 9; ++j) Xsh[tid][j] = R[j];
        #pragma unroll
        for (int j = 0; j < 3; ++j) Xsh[tid][9+j] = tt[j];
    }
    for (int i = tid; i < 1536; i += 256) w0xiL[i] = (__bf16)W0[(size_t)4096*256 + i];
    for (int i = tid; i < 1536; i += 256) {
        int j = i >> 8, k = i & 255;
        woutT[i] = (__bf16)Wout[(size_t)k*6 + j];
    }
    __syncthreads();

    for (int s = 0; s < ns; ++s) {
        ctL[tid] = ct[s*256 + tid];
        if (tid < 32) {
            float R[9], p[3], xi[6];
            #pragma unroll
            for (int j = 0; j < 9; ++j) R[j] = Xsh[tid][j];
            #pragma unroll
            for (int j = 0; j < 3; ++j) p[j] = Xsh[tid][9+j];
            log_se3_dev(R, p, xi);
            #pragma unroll
            for (int j = 0; j < 6; ++j) xiL[tid*6 + j] = xi[j];
        }
        __syncthreads();

        // ---------------- layer 0 (VALU): 8 threads/row x 32 cols ----------------
        float gv[32];
        {
            float xr[6];
            #pragma unroll
            for (int j = 0; j < 6; ++j) xr[j] = xiL[prow*6 + j];
            const float* hp = hproj + (size_t)(m0 + prow)*256 + pcb;
            #pragma unroll
            for (int c8 = 0; c8 < 4; ++c8) {
                float4 h0 = *(const float4*)(hp + c8*8);
                float4 h1 = *(const float4*)(hp + c8*8 + 4);
                float4 c0 = *(const float4*)(ctL + pcb + c8*8);
                float4 c1 = *(const float4*)(ctL + pcb + c8*8 + 4);
                float pr[8] = { h0.x + c0.x, h0.y + c0.y, h0.z + c0.z, h0.w + c0.w,
                                h1.x + c1.x, h1.y + c1.y, h1.z + c1.z, h1.w + c1.w };
                #pragma unroll
                for (int j = 0; j < 6; ++j) {
                    bf16_8 wv = *(const bf16_8*)(w0xiL + j*256 + pcb + c8*8);
                    #pragma unroll
                    for (int e = 0; e < 8; ++e) pr[e] += xr[j] * (float)wv[e];
                }
                #pragma unroll
                for (int e = 0; e < 8; ++e) gv[c8*8 + e] = gelu_f(pr[e]);
            }
            float ps = 0.f, pq = 0.f;
            #pragma unroll
            for (int c = 0; c < 32; ++c) { ps += gv[c]; pq += gv[c]*gv[c]; }
            rowred[prow*16 + (tid & 7)*2 + 0] = ps;
            rowred[prow*16 + (tid & 7)*2 + 1] = pq;
        }
        __syncthreads();
        if (tid < 32) {
            float sm = 0.f, sq = 0.f;
            #pragma unroll
            for (int k = 0; k < 8; ++k) { sm += rowred[tid*16 + k*2]; sq += rowred[tid*16 + k*2 + 1]; }
            float mean = sm * (1.f/256.f);
            float var  = sq * (1.f/256.f) - mean*mean;
            rowred[tid*16 + 0] = mean;
            rowred[tid*16 + 1] = rsqrtf(var + 1e-5f);
        }
        __syncthreads();
        {
            float mean = rowred[prow*16 + 0], rstd = rowred[prow*16 + 1];
            #pragma unroll
            for (int c8 = 0; c8 < 4; ++c8) {
                float4 ga = *(const float4*)(g0 + pcb + c8*8);
                float4 gb = *(const float4*)(g0 + pcb + c8*8 + 4);
                float4 ba = *(const float4*)(be0 + pcb + c8*8);
                float4 bb = *(const float4*)(be0 + pcb + c8*8 + 4);
                bf16_8 v8;
                v8[0] = (__bf16)((gv[c8*8+0] - mean)*rstd*ga.x + ba.x);
                v8[1] = (__bf16)((gv[c8*8+1] - mean)*rstd*ga.y + ba.y);
                v8[2] = (__bf16)((gv[c8*8+2] - mean)*rstd*ga.z + ba.z);
                v8[3] = (__bf16)((gv[c8*8+3] - mean)*rstd*ga.w + ba.w);
                v8[4] = (__bf16)((gv[c8*8+4] - mean)*rstd*gb.x + bb.x);
                v8[5] = (__bf16)((gv[c8*8+5] - mean)*rstd*gb.y + bb.y);
                v8[6] = (__bf16)((gv[c8*8+6] - mean)*rstd*gb.z + bb.z);
                v8[7] = (__bf16)((gv[c8*8+7] - mean)*rstd*gb.w + bb.w);
                *(bf16_8*)(Ysh + prow*264 + pcb + c8*8) = v8;
            }
        }
        __syncthreads();

        // ---------------- layers 1..3: MFMA, W-frags straight from L2 ----------------
        #pragma unroll 1
        for (int L = 0; L < 3; ++L) {
            f32x4 acc[2][4];
            const f32x4 zv = {0.f, 0.f, 0.f, 0.f};
            #pragma unroll
            for (int a = 0; a < 2; ++a)
                #pragma unroll
                for (int b = 0; b < 4; ++b) acc[a][b] = zv;
            const __bf16* wfrag = WrT2 + (size_t)L*128*512 + (size_t)l*8;
            #pragma unroll
            for (int sl = 0; sl < 8; ++sl) {
                bf16_8 af[2], bfv[4];
                #pragma unroll
                for (int mt = 0; mt < 2; ++mt)
                    af[mt] = *(const bf16_8*)(Ysh + (mt*16 + ln)*264 + sl*32 + q*8);
                #pragma unroll
                for (int nt = 0; nt < 4; ++nt)
                    bfv[nt] = *(const bf16_8*)(wfrag + (size_t)(sl*16 + w + nt*4)*512);
                #pragma unroll
                for (int mt = 0; mt < 2; ++mt)
                    #pragma unroll
                    for (int nt = 0; nt < 4; ++nt)
                        acc[mt][nt] = __builtin_amdgcn_mfma_f32_16x16x32_bf16(af[mt], bfv[nt], acc[mt][nt], 0, 0, 0);
            }
            // epilogue: bias + gelu + LN, write Y
            const float* brL = br + L*256;
            const float* grL = gr + L*256;
            const float* beL = ber + L*256;
            float gelv[2][4][4];
            float ps[2][4], pq2[2][4];
            #pragma unroll
            for (int mt = 0; mt < 2; ++mt)
                #pragma unroll
                for (int r = 0; r < 4; ++r) { ps[mt][r] = 0.f; pq2[mt][r] = 0.f; }
            #pragma unroll
            for (int nt = 0; nt < 4; ++nt) {
                int col = (w + nt*4)*16 + ln;
                float bb = brL[col];
                #pragma unroll
                for (int mt = 0; mt < 2; ++mt)
                    #pragma unroll
                    for (int r = 0; r < 4; ++r) {
                        float u = gelu_f(acc[mt][nt][r] + bb);
                        gelv[mt][nt][r] = u;
                        ps[mt][r] += u;
                        pq2[mt][r] += u*u;
                    }
            }
            #pragma unroll
            for (int off = 1; off < 16; off <<= 1)
                #pragma unroll
                for (int mt = 0; mt < 2; ++mt)
                    #pragma unroll
                    for (int r = 0; r < 4; ++r) {
                        ps[mt][r]  += __shfl_xor(ps[mt][r],  off, 64);
                        pq2[mt][r] += __shfl_xor(pq2[mt][r], off, 64);
                    }
            if (ln == 0)
                #pragma unroll
                for (int mt = 0; mt < 2; ++mt)
                    #pragma unroll
                    for (int r = 0; r < 4; ++r) {
                        int row = mt*16 + q*4 + r;
                        rowred[row*16 + w*2 + 0] = ps[mt][r];
                        rowred[row*16 + w*2 + 1] = pq2[mt][r];
                    }
            __syncthreads();
            if (tid < 32) {
                float sm = 0.f, sq = 0.f;
                #pragma unroll
                for (int k = 0; k < 4; ++k) { sm += rowred[tid*16 + k*2]; sq += rowred[tid*16 + k*2 + 1]; }
                float mean = sm * (1.f/256.f);
                float var  = sq * (1.f/256.f) - mean*mean;
                rowred[tid*16 + 0] = mean;
                rowred[tid*16 + 1] = rsqrtf(var + 1e-5f);
            }
            __syncthreads();
            #pragma unroll
            for (int nt = 0; nt < 4; ++nt) {
                int col = (w + nt*4)*16 + ln;
                float gg = grL[col], bb2 = beL[col];
                #pragma unroll
                for (int mt = 0; mt < 2; ++mt)
                    #pragma unroll
                    for (int r = 0; r < 4; ++r) {
                        int row = mt*16 + q*4 + r;
                        float mean = rowred[row*16 + 0];
                        float rstd = rowred[row*16 + 1];
                        Ysh[row*264 + col] = (__bf16)((gelv[mt][nt][r] - mean)*rstd*gg + bb2);
                    }
            }
            __syncthreads();
        }

        // v = Y @ Wout (8 threads/row, 32-k chunks)
        {
            float p6[6] = {0.f, 0.f, 0.f, 0.f, 0.f, 0.f};
            const int kb = (tid & 7) * 32;
            #pragma unroll
            for (int kc = 0; kc < 4; ++kc) {
                bf16_8 yv = *(const bf16_8*)(Ysh + prow*264 + kb + kc*8);
                float yf[8];
                #pragma unroll
                for (int e = 0; e < 8; ++e) yf[e] = (float)yv[e];
                #pragma unroll
                for (int j = 0; j < 6; ++j) {
                    bf16_8 wv = *(const bf16_8*)(woutT + j*256 + kb + kc*8);
                    #pragma unroll
                    for (int e = 0; e < 8; ++e) p6[j] += yf[e] * (float)wv[e];
                }
            }
            #pragma unroll
            for (int j = 0; j < 6; ++j) vpart[(prow*8 + (tid & 7))*6 + j] = p6[j];
        }
        __syncthreads();
        if (tid < 32) {
            float v6[6];
            #pragma unroll
            for (int j = 0; j < 6; ++j) {
                float sv = 0.f;
                #pragma unroll
                for (int c = 0; c < 8; ++c) sv += vpart[(tid*8 + c)*6 + j];
                v6[j] = dt * (sv + bout[j]);
            }
            float Re[9], te[3];
            exp_se3_dev(v6, Re, te);
            float R0[9], t0[3];
            #pragma unroll
            for (int j = 0; j < 9; ++j) R0[j] = Xsh[tid][j];
            #pragma unroll
            for (int j = 0; j < 3; ++j) t0[j] = Xsh[tid][9+j];
            float Rn[9], tn[3];
            #pragma unroll
            for (int i = 0; i < 3; ++i)
                #pragma unroll
                for (int j2 = 0; j2 < 3; ++j2)
                    Rn[i*3+j2] = R0[i*3+0]*Re[0*3+j2] + R0[i*3+1]*Re[1*3+j2] + R0[i*3+2]*Re[2*3+j2];
            #pragma unroll
            for (int i = 0; i < 3; ++i)
                tn[i] = R0[i*3+0]*te[0] + R0[i*3+1]*te[1] + R0[i*3+2]*te[2] + t0[i];
            #pragma unroll
            for (int j = 0; j < 9; ++j) Xsh[tid][j] = Rn[j];
            #pragma unroll
            for (int j = 0; j < 3; ++j) Xsh[tid][9+j] = tn[j];
            if (s == ns - 1) {
                float* o = out + (size_t)(m0 + tid)*16;
                o[0]  = Rn[0]; o[1]  = Rn[1]; o[2]  = Rn[2]; o[3]  = tn[0];
                o[4]  = Rn[3]; o[5]  = Rn[4]; o[6]  = Rn[5]; o[7]  = tn[1];
                o[8]  = Rn[6]; o[9]  = Rn[7]; o[10] = Rn[8]; o[11] = tn[2];
                o[12] = 0.f; o[13] = 0.f; o[14] = 0.f; o[15] = 1.f;
            }
        }
        __syncthreads();
    }
}

extern "C" void kernel_launch(void* const* d_in, const int* in_sizes, int n_in,
                              void* d_out, int out_size, void* d_ws, size_t ws_size,
                              hipStream_t stream) {
    const float* h    = (const float*)d_in[0];
    const float* xi0  = (const float*)d_in[1];
    const float* W0   = (const float*)d_in[2];
    const float* b0   = (const float*)d_in[3];
    const float* g0   = (const float*)d_in[4];
    const float* be0  = (const float*)d_in[5];
    const float* Wr   = (const float*)d_in[6];
    const float* br   = (const float*)d_in[7];
    const float* gr   = (const float*)d_in[8];
    const float* ber  = (const float*)d_in[9];
    const float* Wout = (const float*)d_in[10];
    const float* bout = (const float*)d_in[11];
    const float* gW1  = (const float*)d_in[12];
    const float* gb1  = (const float*)d_in[13];
    const float* gW2  = (const float*)d_in[14];
    const float* gb2  = (const float*)d_in[15];
    const int*   nsp  = (const int*)d_in[16];
    float* out = (float*)d_out;

    char* ws = (char*)d_ws;
    float*  hproj = (float*)(ws + WS_HPROJ);
    __bf16* BT2   = (__bf16*)(ws + WS_BT);   // 2560*512*2 = 2,621,440 B
    __bf16* WrT2  = (__bf16*)(ws + WS_WRT);  //  384*512*2 =   393,216 B
    float*  ct    = (float*)(ws + WS_CT);

    prep_frag<<<736, 256, 0, stream>>>(W0, gW1, Wr, BT2, WrT2);
    prep_ct<<<16, 256, 0, stream>>>(W0, b0, nsp, ct);
    k2<<<512, 256, 0, stream>>>(h, BT2, gb1, gW2, gb2, hproj, out + (size_t)16384*16);
    k3<<<512, 256, 0, stream>>>(hproj, WrT2, ct, W0, Wout, bout, br, gr, ber, g0, be0, xi0, nsp, out);
}

// Round 4
// 779.110 us; speedup vs baseline: 1.5384x; 1.1002x over previous
//
#include <hip/hip_runtime.h>
#include <math.h>

typedef __attribute__((ext_vector_type(8))) __bf16 bf16_8;
typedef __attribute__((ext_vector_type(4))) float f32x4;

#define WS_HPROJ 0
#define WS_BT    16777216
#define WS_WRT   19398656
#define WS_CT    19791872

__device__ __forceinline__ float gelu_f(float x) {
    return 0.5f * x * (1.0f + erff(0.70710678118654752440f * x));
}

__device__ __forceinline__ void exp_se3_dev(const float xi[6], float R[9], float t[3]) {
    float wx = xi[0], wy = xi[1], wz = xi[2];
    float vx = xi[3], vy = xi[4], vz = xi[5];
    float ww = wx*wx + wy*wy + wz*wz;
    float th2 = ww + 1e-20f;
    float th = sqrtf(th2);
    float A, Bc, Cc;
    if (th < 1e-3f) {
        A = 1.f - th2*(1.f/6.f);
        Bc = 0.5f - th2*(1.f/24.f);
        Cc = (1.f/6.f) - th2*(1.f/120.f);
    } else {
        float s = sinf(th), c = cosf(th);
        A = s/th;
        Bc = (1.f - c)/th2;
        Cc = (th - s)/(th2*th);
    }
    float W2[9] = { wx*wx - ww, wx*wy,       wx*wz,
                    wy*wx,      wy*wy - ww,  wy*wz,
                    wz*wx,      wz*wy,       wz*wz - ww };
    R[0] = 1.f + Bc*W2[0];  R[1] = -A*wz + Bc*W2[1]; R[2] =  A*wy + Bc*W2[2];
    R[3] =  A*wz + Bc*W2[3]; R[4] = 1.f + Bc*W2[4];  R[5] = -A*wx + Bc*W2[5];
    R[6] = -A*wy + Bc*W2[6]; R[7] =  A*wx + Bc*W2[7]; R[8] = 1.f + Bc*W2[8];
    float V[9];
    V[0] = 1.f + Cc*W2[0];   V[1] = -Bc*wz + Cc*W2[1]; V[2] =  Bc*wy + Cc*W2[2];
    V[3] =  Bc*wz + Cc*W2[3]; V[4] = 1.f + Cc*W2[4];   V[5] = -Bc*wx + Cc*W2[5];
    V[6] = -Bc*wy + Cc*W2[6]; V[7] =  Bc*wx + Cc*W2[7]; V[8] = 1.f + Cc*W2[8];
    t[0] = V[0]*vx + V[1]*vy + V[2]*vz;
    t[1] = V[3]*vx + V[4]*vy + V[5]*vz;
    t[2] = V[6]*vx + V[7]*vy + V[8]*vz;
}

__device__ __forceinline__ void log_se3_dev(const float R[9], const float p[3], float xi[6]) {
    float tr = R[0] + R[4] + R[8];
    float c = 0.5f*(tr - 1.f);
    c = fminf(fmaxf(c, -1.f + 1e-7f), 1.f - 1e-7f);
    float th = acosf(c);
    float fac, D;
    if (th < 1e-3f) {
        fac = 0.5f + th*th*(1.f/12.f);
        D = 1.f/12.f;
    } else {
        float s = sinf(th), co = cosf(th);
        fac = th/(2.f*s);
        D = (1.f - th*s/(2.f*(1.f - co)))/(th*th);
    }
    float wx = fac*(R[7] - R[5]);
    float wy = fac*(R[2] - R[6]);
    float wz = fac*(R[3] - R[1]);
    float ww = wx*wx + wy*wy + wz*wz;
    float W2[9] = { wx*wx - ww, wx*wy,       wx*wz,
                    wy*wx,      wy*wy - ww,  wy*wz,
                    wz*wx,      wz*wy,       wz*wz - ww };
    float Vi[9];
    Vi[0] = 1.f + D*W2[0];    Vi[1] =  0.5f*wz + D*W2[1]; Vi[2] = -0.5f*wy + D*W2[2];
    Vi[3] = -0.5f*wz + D*W2[3]; Vi[4] = 1.f + D*W2[4];    Vi[5] =  0.5f*wx + D*W2[5];
    Vi[6] =  0.5f*wy + D*W2[6]; Vi[7] = -0.5f*wx + D*W2[7]; Vi[8] = 1.f + D*W2[8];
    xi[0] = wx; xi[1] = wy; xi[2] = wz;
    xi[3] = Vi[0]*p[0] + Vi[1]*p[1] + Vi[2]*p[2];
    xi[4] = Vi[3]*p[0] + Vi[4]*p[1] + Vi[5]*p[2];
    xi[5] = Vi[6]*p[0] + Vi[7]*p[1] + Vi[8]*p[2];
}

// ---------------------------------------------------------------------------
// prep_frag: pack weights into MFMA-fragment order (bf16).
//  BT2 tile t = s*20 + ntg  (s = k/32 in 0..127, ntg in 0..19 over 320 cols):
//    BT2[t*512 + l*8 + e] = Wfull[k = s*32 + (l>>4)*8 + e][col = ntg*16 + (l&15)]
//    where Wfull = W0[:4096] cols 0..255 | gW1 cols 256..319
//  WrT2 tile t2 = L*128 + sl*16 + ntg (sl in 0..7, ntg in 0..15):
//    WrT2[t2*512 + l*8 + e] = Wr[L][k = sl*32 + (l>>4)*8 + e][col = ntg*16 + (l&15)]
// ---------------------------------------------------------------------------
__global__ void prep_frag(const float* __restrict__ W0, const float* __restrict__ gW1,
                          const float* __restrict__ Wr, __bf16* __restrict__ BT2,
                          __bf16* __restrict__ WrT2) {
    const int tid = threadIdx.x;
    const int l = tid & 63, q = l >> 4, ln = l & 15;
    if (blockIdx.x < 640) {
        const int t = blockIdx.x * 4 + (tid >> 6);
        const int s = t / 20, ntg = t % 20;
        const int col = ntg*16 + ln;
        const int kbase = s*32 + q*8;
        bf16_8 o;
        if (col < 256) {
            #pragma unroll
            for (int e = 0; e < 8; ++e) o[e] = (__bf16)W0[(size_t)(kbase+e)*256 + col];
        } else {
            #pragma unroll
            for (int e = 0; e < 8; ++e) o[e] = (__bf16)gW1[(size_t)(kbase+e)*64 + (col-256)];
        }
        *(bf16_8*)(BT2 + (size_t)t*512 + l*8) = o;
    } else {
        const int t2 = (blockIdx.x - 640) * 4 + (tid >> 6);
        const int L = t2 >> 7, rem = t2 & 127, sl = rem >> 4, ntg = rem & 15;
        const int col = ntg*16 + ln;
        const int kbase = sl*32 + q*8;
        bf16_8 o;
        #pragma unroll
        for (int e = 0; e < 8; ++e)
            o[e] = (__bf16)Wr[(size_t)L*65536 + (size_t)(kbase+e)*256 + col];
        *(bf16_8*)(WrT2 + (size_t)t2*512 + l*8) = o;
    }
}

// ct[s][col] = b0[col] + temb(s/ns) @ W0[4102:4166]
__global__ void prep_ct(const float* __restrict__ W0, const float* __restrict__ b0,
                        const int* __restrict__ nsp, float* __restrict__ ct) {
    int s = blockIdx.x;
    int ns = *nsp;
    if (s >= ns) return;
    int col = threadIdx.x;
    float t = (float)s / (float)ns;
    float acc = b0[col];
    #pragma unroll
    for (int d = 0; d < 32; d++) {
        float f = expf((float)d * -0.29710775393471563f);  // -ln(10000)/31
        float e = t * f;
        acc += sinf(e) * W0[(size_t)(4102 + d)*256 + col];
        acc += cosf(e) * W0[(size_t)(4134 + d)*256 + col];
    }
    ct[s*256 + col] = acc;
}

// ---------------------------------------------------------------------------
// k2 v3: h_proj = h @ W0[:4096] + fused gripper head.
// A (h, fp32) cooperatively staged once per block into LDS (bf16, 72-stride),
// non-temporal global loads so the h-stream does NOT evict BT2 from L2.
// B-frags direct from L2 (fragment-packed BT2), double-buffered in regs.
// Raw s_barrier + lgkmcnt(0) only (no vmcnt drain) -> A/B global loads stay
// in flight across barriers (counted-vmcnt pipeline via compiler auto-waits).
// M-tile 32, grid 512 -> 2 blocks/CU with independent barrier groups.
// ---------------------------------------------------------------------------
__device__ __forceinline__ void k2_issueA(f32x4 (&P)[2], const float* hrow, int st) {
    P[0] = __builtin_nontemporal_load((const f32x4*)(hrow + st*64));
    P[1] = __builtin_nontemporal_load((const f32x4*)(hrow + st*64 + 4));
}
__device__ __forceinline__ void k2_writeA(__bf16* dst, const f32x4 (&P)[2]) {
    bf16_8 v;
    v[0]=(__bf16)P[0][0]; v[1]=(__bf16)P[0][1]; v[2]=(__bf16)P[0][2]; v[3]=(__bf16)P[0][3];
    v[4]=(__bf16)P[1][0]; v[5]=(__bf16)P[1][1]; v[6]=(__bf16)P[1][2]; v[7]=(__bf16)P[1][3];
    *(bf16_8*)dst = v;
}
__device__ __forceinline__ void k2_issueB(bf16_8 (&Bv)[2][5], const __bf16* bbase, int st) {
    #pragma unroll
    for (int kk = 0; kk < 2; ++kk)
        #pragma unroll
        for (int jn = 0; jn < 5; ++jn)
            Bv[kk][jn] = *(const bf16_8*)(bbase + (size_t)((st*2 + kk)*20 + jn*4)*512);
}
__device__ __forceinline__ void k2_mm2(f32x4 (&acc)[2][5], const __bf16* Ab, int ln, int q,
                                       const bf16_8 (&Bv)[2][5]) {
    #pragma unroll
    for (int kk = 0; kk < 2; ++kk) {
        bf16_8 af[2];
        af[0] = *(const bf16_8*)(Ab + (0*16 + ln)*72 + kk*32 + q*8);
        af[1] = *(const bf16_8*)(Ab + (1*16 + ln)*72 + kk*32 + q*8);
        #pragma unroll
        for (int mt = 0; mt < 2; ++mt)
            #pragma unroll
            for (int jn = 0; jn < 5; ++jn)
                acc[mt][jn] = __builtin_amdgcn_mfma_f32_16x16x32_bf16(af[mt], Bv[kk][jn], acc[mt][jn], 0, 0, 0);
    }
}

__launch_bounds__(256, 2)
__global__ void k2(const float* __restrict__ h, const __bf16* __restrict__ BT2,
                   const float* __restrict__ gb1, const float* __restrict__ gW2,
                   const float* __restrict__ gb2, float* __restrict__ hproj,
                   float* __restrict__ grip) {
    __shared__ __align__(16) __bf16 Abuf0[32*72];
    __shared__ __align__(16) __bf16 Abuf1[32*72];
    __shared__ float gpart[32][4];

    const int tid = threadIdx.x;
    const int w = tid >> 6;
    const int l = tid & 63;
    const int q = l >> 4;
    const int ln = l & 15;
    const int m0 = blockIdx.x * 32;

    // staging role: thread -> (row, col-chunk) of the 32x64 A step-tile
    const int r  = tid >> 3;
    const int c0 = (tid & 7) * 8;
    const float* hrow = h + (size_t)(m0 + r)*4096 + c0;
    __bf16* aw0 = Abuf0 + r*72 + c0;
    __bf16* aw1 = Abuf1 + r*72 + c0;

    const __bf16* bbase = BT2 + (size_t)w*512 + (size_t)l*8;

    f32x4 acc[2][5];
    const f32x4 zv = {0.f, 0.f, 0.f, 0.f};
    #pragma unroll
    for (int a = 0; a < 2; ++a)
        #pragma unroll
        for (int b = 0; b < 5; ++b) acc[a][b] = zv;

    f32x4 PA[2], PB[2];
    bf16_8 B0[2][5], B1[2][5];

    // prologue: fill buf0 (st=0), have A(1),A(2) + B(0),B(1) in flight
    k2_issueA(PA, hrow, 0);
    k2_issueB(B0, bbase, 0);
    k2_issueA(PB, hrow, 1);
    k2_issueB(B1, bbase, 1);
    k2_writeA(aw0, PA);          // waits PA only
    k2_issueA(PA, hrow, 2);
    asm volatile("s_waitcnt lgkmcnt(0)" ::: "memory");
    __builtin_amdgcn_s_barrier();

    #pragma unroll 1
    for (int t = 0; t < 32; ++t) {
        const int st = 2*t;
        // ---- even step st: compute buf0 with B0 ----
        k2_mm2(acc, Abuf0, ln, q, B0);
        k2_writeA(aw1, PB);                       // A(st+1) -> buf1
        if (st + 3 < 64) k2_issueA(PB, hrow, st + 3);
        if (st + 2 < 64) k2_issueB(B0, bbase, st + 2);
        asm volatile("s_waitcnt lgkmcnt(0)" ::: "memory");
        __builtin_amdgcn_s_barrier();
        // ---- odd step st+1: compute buf1 with B1 ----
        k2_mm2(acc, Abuf1, ln, q, B1);
        if (st + 2 < 64) {
            k2_writeA(aw0, PA);                   // A(st+2) -> buf0
            if (st + 4 < 64) k2_issueA(PA, hrow, st + 4);
            if (st + 3 < 64) k2_issueB(B1, bbase, st + 3);
            asm volatile("s_waitcnt lgkmcnt(0)" ::: "memory");
            __builtin_amdgcn_s_barrier();
        }
    }

    // epilogue: h_proj columns (jn 0..3)
    #pragma unroll
    for (int mt = 0; mt < 2; ++mt)
        #pragma unroll
        for (int jn = 0; jn < 4; ++jn) {
            int col = (w + jn*4)*16 + ln;
            #pragma unroll
            for (int r2 = 0; r2 < 4; ++r2) {
                int row = mt*16 + q*4 + r2;
                hproj[(size_t)(m0 + row)*256 + col] = acc[mt][jn][r2];
            }
        }
    // gripper columns (jn = 4 -> ntg = w+16 -> gW1 cols w*16..w*16+15)
    {
        int cg = w*16 + ln;
        float b1v = gb1[cg];
        float w2v = gW2[cg];
        float ps[2][4];
        #pragma unroll
        for (int mt = 0; mt < 2; ++mt)
            #pragma unroll
            for (int r2 = 0; r2 < 4; ++r2)
                ps[mt][r2] = gelu_f(acc[mt][4][r2] + b1v) * w2v;
        #pragma unroll
        for (int off = 1; off < 16; off <<= 1)
            #pragma unroll
            for (int mt = 0; mt < 2; ++mt)
                #pragma unroll
                for (int r2 = 0; r2 < 4; ++r2)
                    ps[mt][r2] += __shfl_xor(ps[mt][r2], off, 64);
        if (ln == 0)
            #pragma unroll
            for (int mt = 0; mt < 2; ++mt)
                #pragma unroll
                for (int r2 = 0; r2 < 4; ++r2)
                    gpart[mt*16 + q*4 + r2][w] = ps[mt][r2];
    }
    __syncthreads();
    if (tid < 32) {
        float g = gpart[tid][0] + gpart[tid][1] + gpart[tid][2] + gpart[tid][3] + gb2[0];
        grip[m0 + tid] = 1.f / (1.f + expf(-g));
    }
}

// ---------------------------------------------------------------------------
// k3: persistent 10-step MLP + SE3 integrator. grid 512 x 256; 32 rows/WG,
// 2 blocks/CU. W-fragments loaded straight from L2 (WrT2) -> no per-slice
// LDS staging, no per-slice barriers.  (UNCHANGED from round 2)
// ---------------------------------------------------------------------------
__launch_bounds__(256, 2)
__global__ void k3(const float* __restrict__ hproj,
                   const __bf16* __restrict__ WrT2,
                   const float* __restrict__ ct,
                   const float* __restrict__ W0,
                   const float* __restrict__ Wout,
                   const float* __restrict__ bout,
                   const float* __restrict__ br,
                   const float* __restrict__ gr,
                   const float* __restrict__ ber,
                   const float* __restrict__ g0,
                   const float* __restrict__ be0,
                   const float* __restrict__ xi0,
                   const int* __restrict__ nsp,
                   float* __restrict__ out) {
    __shared__ __align__(16) __bf16 Ysh[32*264];   // 16896 B
    __shared__ float xiL[32*6];                    //   768 B
    __shared__ float rowred[32*16];                //  2048 B
    __shared__ float vpart[32*8*6];                //  6144 B
    __shared__ __align__(16) __bf16 woutT[6*256];  //  3072 B
    __shared__ float Xsh[32][12];                  //  1536 B
    __shared__ float ctL[256];                     //  1024 B
    __shared__ __align__(16) __bf16 w0xiL[6*256];  //  3072 B

    const int tid = threadIdx.x;
    const int w = tid >> 6;
    const int l = tid & 63;
    const int q = l >> 4;
    const int ln = l & 15;
    const int m0 = blockIdx.x * 32;
    const int ns = *nsp;
    const float dt = 1.0f / (float)ns;

    const int prow = tid >> 3;          // 0..31
    const int pcb  = (tid & 7) * 32;    // 32-col chunk

    if (tid < 32) {
        float xi[6];
        #pragma unroll
        for (int j = 0; j < 6; ++j) xi[j] = 0.1f * xi0[(size_t)(m0 + tid)*6 + j];
        float R[9], tt[3];
        exp_se3_dev(xi, R, tt);
        #pragma unroll
        for (int j = 0; j < 9; ++j) Xsh[tid][j] = R[j];
        #pragma unroll
        for (int j = 0; j < 3; ++j) Xsh[tid][9+j] = tt[j];
    }
    for (int i = tid; i < 1536; i += 256) w0xiL[i] = (__bf16)W0[(size_t)4096*256 + i];
    for (int i = tid; i < 1536; i += 256) {
        int j = i >> 8, k = i & 255;
        woutT[i] = (__bf16)Wout[(size_t)k*6 + j];
    }
    __syncthreads();

    for (int s = 0; s < ns; ++s) {
        ctL[tid] = ct[s*256 + tid];
        if (tid < 32) {
            float R[9], p[3], xi[6];
            #pragma unroll
            for (int j = 0; j < 9; ++j) R[j] = Xsh[tid][j];
            #pragma unroll
            for (int j = 0; j < 3; ++j) p[j] = Xsh[tid][9+j];
            log_se3_dev(R, p, xi);
            #pragma unroll
            for (int j = 0; j < 6; ++j) xiL[tid*6 + j] = xi[j];
        }
        __syncthreads();

        // ---------------- layer 0 (VALU): 8 threads/row x 32 cols ----------------
        float gv[32];
        {
            float xr[6];
            #pragma unroll
            for (int j = 0; j < 6; ++j) xr[j] = xiL[prow*6 + j];
            const float* hp = hproj + (size_t)(m0 + prow)*256 + pcb;
            #pragma unroll
            for (int c8 = 0; c8 < 4; ++c8) {
                float4 h0 = *(const float4*)(hp + c8*8);
                float4 h1 = *(const float4*)(hp + c8*8 + 4);
                float4 c0 = *(const float4*)(ctL + pcb + c8*8);
                float4 c1 = *(const float4*)(ctL + pcb + c8*8 + 4);
                float pr[8] = { h0.x + c0.x, h0.y + c0.y, h0.z + c0.z, h0.w + c0.w,
                                h1.x + c1.x, h1.y + c1.y, h1.z + c1.z, h1.w + c1.w };
                #pragma unroll
                for (int j = 0; j < 6; ++j) {
                    bf16_8 wv = *(const bf16_8*)(w0xiL + j*256 + pcb + c8*8);
                    #pragma unroll
                    for (int e = 0; e < 8; ++e) pr[e] += xr[j] * (float)wv[e];
                }
                #pragma unroll
                for (int e = 0; e < 8; ++e) gv[c8*8 + e] = gelu_f(pr[e]);
            }
            float ps = 0.f, pq = 0.f;
            #pragma unroll
            for (int c = 0; c < 32; ++c) { ps += gv[c]; pq += gv[c]*gv[c]; }
            rowred[prow*16 + (tid & 7)*2 + 0] = ps;
            rowred[prow*16 + (tid & 7)*2 + 1] = pq;
        }
        __syncthreads();
        if (tid < 32) {
            float sm = 0.f, sq = 0.f;
            #pragma unroll
            for (int k = 0; k < 8; ++k) { sm += rowred[tid*16 + k*2]; sq += rowred[tid*16 + k*2 + 1]; }
            float mean = sm * (1.f/256.f);
            float var  = sq * (1.f/256.f) - mean*mean;
            rowred[tid*16 + 0] = mean;
            rowred[tid*16 + 1] = rsqrtf(var + 1e-5f);
        }
        __syncthreads();
        {
            float mean = rowred[prow*16 + 0], rstd = rowred[prow*16 + 1];
            #pragma unroll
            for (int c8 = 0; c8 < 4; ++c8) {
                float4 ga = *(const float4*)(g0 + pcb + c8*8);
                float4 gb = *(const float4*)(g0 + pcb + c8*8 + 4);
                float4 ba = *(const float4*)(be0 + pcb + c8*8);
                float4 bb = *(const float4*)(be0 + pcb + c8*8 + 4);
                bf16_8 v8;
                v8[0] = (__bf16)((gv[c8*8+0] - mean)*rstd*ga.x + ba.x);
                v8[1] = (__bf16)((gv[c8*8+1] - mean)*rstd*ga.y + ba.y);
                v8[2] = (__bf16)((gv[c8*8+2] - mean)*rstd*ga.z + ba.z);
                v8[3] = (__bf16)((gv[c8*8+3] - mean)*rstd*ga.w + ba.w);
                v8[4] = (__bf16)((gv[c8*8+4] - mean)*rstd*gb.x + bb.x);
                v8[5] = (__bf16)((gv[c8*8+5] - mean)*rstd*gb.y + bb.y);
                v8[6] = (__bf16)((gv[c8*8+6] - mean)*rstd*gb.z + bb.z);
                v8[7] = (__bf16)((gv[c8*8+7] - mean)*rstd*gb.w + bb.w);
                *(bf16_8*)(Ysh + prow*264 + pcb + c8*8) = v8;
            }
        }
        __syncthreads();

        // ---------------- layers 1..3: MFMA, W-frags straight from L2 ----------------
        #pragma unroll 1
        for (int L = 0; L < 3; ++L) {
            f32x4 acc[2][4];
            const f32x4 zv = {0.f, 0.f, 0.f, 0.f};
            #pragma unroll
            for (int a = 0; a < 2; ++a)
                #pragma unroll
                for (int b = 0; b < 4; ++b) acc[a][b] = zv;
            const __bf16* wfrag = WrT2 + (size_t)L*128*512 + (size_t)l*8;
            #pragma unroll
            for (int sl = 0; sl < 8; ++sl) {
                bf16_8 af[2], bfv[4];
                #pragma unroll
                for (int mt = 0; mt < 2; ++mt)
                    af[mt] = *(const bf16_8*)(Ysh + (mt*16 + ln)*264 + sl*32 + q*8);
                #pragma unroll
                for (int nt = 0; nt < 4; ++nt)
                    bfv[nt] = *(const bf16_8*)(wfrag + (size_t)(sl*16 + w + nt*4)*512);
                #pragma unroll
                for (int mt = 0; mt < 2; ++mt)
                    #pragma unroll
                    for (int nt = 0; nt < 4; ++nt)
                        acc[mt][nt] = __builtin_amdgcn_mfma_f32_16x16x32_bf16(af[mt], bfv[nt], acc[mt][nt], 0, 0, 0);
            }
            // epilogue: bias + gelu + LN, write Y
            const float* brL = br + L*256;
            const float* grL = gr + L*256;
            const float* beL = ber + L*256;
            float gelv[2][4][4];
            float ps[2][4], pq2[2][4];
            #pragma unroll
            for (int mt = 0; mt < 2; ++mt)
                #pragma unroll
                for (int r = 0; r < 4; ++r) { ps[mt][r] = 0.f; pq2[mt][r] = 0.f; }
            #pragma unroll
            for (int nt = 0; nt < 4; ++nt) {
                int col = (w + nt*4)*16 + ln;
                float bb = brL[col];
                #pragma unroll
                for (int mt = 0; mt < 2; ++mt)
                    #pragma unroll
                    for (int r = 0; r < 4; ++r) {
                        float u = gelu_f(acc[mt][nt][r] + bb);
                        gelv[mt][nt][r] = u;
                        ps[mt][r] += u;
                        pq2[mt][r] += u*u;
                    }
            }
            #pragma unroll
            for (int off = 1; off < 16; off <<= 1)
                #pragma unroll
                for (int mt = 0; mt < 2; ++mt)
                    #pragma unroll
                    for (int r = 0; r < 4; ++r) {
                        ps[mt][r]  += __shfl_xor(ps[mt][r],  off, 64);
                        pq2[mt][r] += __shfl_xor(pq2[mt][r], off, 64);
                    }
            if (ln == 0)
                #pragma unroll
                for (int mt = 0; mt < 2; ++mt)
                    #pragma unroll
                    for (int r = 0; r < 4; ++r) {
                        int row = mt*16 + q*4 + r;
                        rowred[row*16 + w*2 + 0] = ps[mt][r];
                        rowred[row*16 + w*2 + 1] = pq2[mt][r];
                    }
            __syncthreads();
            if (tid < 32) {
                float sm = 0.f, sq = 0.f;
                #pragma unroll
                for (int k = 0; k < 4; ++k) { sm += rowred[tid*16 + k*2]; sq += rowred[tid*16 + k*2 + 1]; }
                float mean = sm * (1.f/256.f);
                float var  = sq * (1.f/256.f) - mean*mean;
                rowred[tid*16 + 0] = mean;
                rowred[tid*16 + 1] = rsqrtf(var + 1e-5f);
            }
            __syncthreads();
            #pragma unroll
            for (int nt = 0; nt < 4; ++nt) {
                int col = (w + nt*4)*16 + ln;
                float gg = grL[col], bb2 = beL[col];
                #pragma unroll
                for (int mt = 0; mt < 2; ++mt)
                    #pragma unroll
                    for (int r = 0; r < 4; ++r) {
                        int row = mt*16 + q*4 + r;
                        float mean = rowred[row*16 + 0];
                        float rstd = rowred[row*16 + 1];
                        Ysh[row*264 + col] = (__bf16)((gelv[mt][nt][r] - mean)*rstd*gg + bb2);
                    }
            }
            __syncthreads();
        }

        // v = Y @ Wout (8 threads/row, 32-k chunks)
        {
            float p6[6] = {0.f, 0.f, 0.f, 0.f, 0.f, 0.f};
            const int kb = (tid & 7) * 32;
            #pragma unroll
            for (int kc = 0; kc < 4; ++kc) {
                bf16_8 yv = *(const bf16_8*)(Ysh + prow*264 + kb + kc*8);
                float yf[8];
                #pragma unroll
                for (int e = 0; e < 8; ++e) yf[e] = (float)yv[e];
                #pragma unroll
                for (int j = 0; j < 6; ++j) {
                    bf16_8 wv = *(const bf16_8*)(woutT + j*256 + kb + kc*8);
                    #pragma unroll
                    for (int e = 0; e < 8; ++e) p6[j] += yf[e] * (float)wv[e];
                }
            }
            #pragma unroll
            for (int j = 0; j < 6; ++j) vpart[(prow*8 + (tid & 7))*6 + j] = p6[j];
        }
        __syncthreads();
        if (tid < 32) {
            float v6[6];
            #pragma unroll
            for (int j = 0; j < 6; ++j) {
                float sv = 0.f;
                #pragma unroll
                for (int c = 0; c < 8; ++c) sv += vpart[(tid*8 + c)*6 + j];
                v6[j] = dt * (sv + bout[j]);
            }
            float Re[9], te[3];
            exp_se3_dev(v6, Re, te);
            float R0[9], t0[3];
            #pragma unroll
            for (int j = 0; j < 9; ++j) R0[j] = Xsh[tid][j];
            #pragma unroll
            for (int j = 0; j < 3; ++j) t0[j] = Xsh[tid][9+j];
            float Rn[9], tn[3];
            #pragma unroll
            for (int i = 0; i < 3; ++i)
                #pragma unroll
                for (int j2 = 0; j2 < 3; ++j2)
                    Rn[i*3+j2] = R0[i*3+0]*Re[0*3+j2] + R0[i*3+1]*Re[1*3+j2] + R0[i*3+2]*Re[2*3+j2];
            #pragma unroll
            for (int i = 0; i < 3; ++i)
                tn[i] = R0[i*3+0]*te[0] + R0[i*3+1]*te[1] + R0[i*3+2]*te[2] + t0[i];
            #pragma unroll
            for (int j = 0; j < 9; ++j) Xsh[tid][j] = Rn[j];
            #pragma unroll
            for (int j = 0; j < 3; ++j) Xsh[tid][9+j] = tn[j];
            if (s == ns - 1) {
                float* o = out + (size_t)(m0 + tid)*16;
                o[0]  = Rn[0]; o[1]  = Rn[1]; o[2]  = Rn[2]; o[3]  = tn[0];
                o[4]  = Rn[3]; o[5]  = Rn[4]; o[6]  = Rn[5]; o[7]  = tn[1];
                o[8]  = Rn[6]; o[9]  = Rn[7]; o[10] = Rn[8]; o[11] = tn[2];
                o[12] = 0.f; o[13] = 0.f; o[14] = 0.f; o[15] = 1.f;
            }
        }
        __syncthreads();
    }
}

extern "C" void kernel_launch(void* const* d_in, const int* in_sizes, int n_in,
                              void* d_out, int out_size, void* d_ws, size_t ws_size,
                              hipStream_t stream) {
    const float* h    = (const float*)d_in[0];
    const float* xi0  = (const float*)d_in[1];
    const float* W0   = (const float*)d_in[2];
    const float* b0   = (const float*)d_in[3];
    const float* g0   = (const float*)d_in[4];
    const float* be0  = (const float*)d_in[5];
    const float* Wr   = (const float*)d_in[6];
    const float* br   = (const float*)d_in[7];
    const float* gr   = (const float*)d_in[8];
    const float* ber  = (const float*)d_in[9];
    const float* Wout = (const float*)d_in[10];
    const float* bout = (const float*)d_in[11];
    const float* gW1  = (const float*)d_in[12];
    const float* gb1  = (const float*)d_in[13];
    const float* gW2  = (const float*)d_in[14];
    const float* gb2  = (const float*)d_in[15];
    const int*   nsp  = (const int*)d_in[16];
    float* out = (float*)d_out;

    char* ws = (char*)d_ws;
    float*  hproj = (float*)(ws + WS_HPROJ);
    __bf16* BT2   = (__bf16*)(ws + WS_BT);   // 2560*512*2 = 2,621,440 B
    __bf16* WrT2  = (__bf16*)(ws + WS_WRT);  //  384*512*2 =   393,216 B
    float*  ct    = (float*)(ws + WS_CT);

    prep_frag<<<736, 256, 0, stream>>>(W0, gW1, Wr, BT2, WrT2);
    prep_ct<<<16, 256, 0, stream>>>(W0, b0, nsp, ct);
    k2<<<512, 256, 0, stream>>>(h, BT2, gb1, gW2, gb2, hproj, out + (size_t)16384*16);
    k3<<<512, 256, 0, stream>>>(hproj, WrT2, ct, W0, Wout, bout, br, gr, ber, g0, be0, xi0, nsp, out);
}